// Round 10
// baseline (1345.009 us; speedup 1.0000x reference)
//
#include <hip/hip_runtime.h>
#include <hip/hip_bf16.h>

#define BDIM 2
#define SDIM 4096
#define EDIM 2048
#define TOK (BDIM * SDIM)       // 8192
#define QK_SCALE 0.08838834764831845f  // 128^-0.5

typedef short bf16x8 __attribute__((ext_vector_type(8)));
typedef float f32x4 __attribute__((ext_vector_type(4)));

__device__ __forceinline__ unsigned short f2bf(float f) {
    unsigned u = __float_as_uint(f);
    u += 0x7FFF + ((u >> 16) & 1);          // RNE; inputs finite
    return (unsigned short)(u >> 16);
}

__device__ __forceinline__ float bf2f(short s) {
    return __uint_as_float(((unsigned)(unsigned short)s) << 16);
}

// fp32x8 -> bf16 hi + bf16 lo (residual), for near-fp32 MFMA via 3-term split
__device__ __forceinline__ void cvt_split8(const float4 a, const float4 b,
                                           bf16x8& hi, bf16x8& lo) {
    float f[8] = {a.x, a.y, a.z, a.w, b.x, b.y, b.z, b.w};
#pragma unroll
    for (int i = 0; i < 8; ++i) {
        const unsigned short h = f2bf(f[i]);
        hi[i] = (short)h;
        const float hf = __uint_as_float(((unsigned)h) << 16);
        lo[i] = (short)f2bf(f[i] - hf);
    }
}

// async 16B global -> LDS (wave-uniform base + lane*16 dest; per-lane source ok)
__device__ __forceinline__ void cp16(const void* g, void* l) {
    __builtin_amdgcn_global_load_lds(
        (const __attribute__((address_space(1))) unsigned int*)g,
        (__attribute__((address_space(3))) unsigned int*)l, 16, 0, 0);
}

// LDS anti-bank-conflict involution on 64B rows (XOR row bits[3:1] -> byte
// bits[6:4]); 16B-granularity-preserving, self-inverse. Proven bit-correct
// with SQ_LDS_BANK_CONFLICT -> 0 in rounds 4/5/6/8/9.
__device__ __forceinline__ int swz(int L) { return L ^ (((L >> 7) & 7) << 4); }

// ---- one-time fp32 -> bf16 hi/lo splits, 3 tensors in one launch ----
__global__ __launch_bounds__(256) void split3_kernel(
    const float* __restrict__ x,  unsigned short* __restrict__ xh,  unsigned short* __restrict__ xl,
    const float* __restrict__ w1, unsigned short* __restrict__ w1h, unsigned short* __restrict__ w1l,
    const float* __restrict__ w2, unsigned short* __restrict__ w2h, unsigned short* __restrict__ w2l) {
    long i = ((long)blockIdx.x * 256 + threadIdx.x) * 8;
    const long n0 = (long)TOK * EDIM;          // 16M elems
    const long n1 = (long)2 * EDIM * EDIM;     // 8M elems
    const float* src; unsigned short *dh, *dl;
    if (i < n0)           { src = x;  dh = xh;  dl = xl;  }
    else if (i < n0 + n1) { i -= n0;      src = w1; dh = w1h; dl = w1l; }
    else                  { i -= n0 + n1; src = w2; dh = w2h; dl = w2l; }
    const float4 f0 = *(const float4*)(src + i);
    const float4 f1 = *(const float4*)(src + i + 4);
    bf16x8 hi, lo;
    cvt_split8(f0, f1, hi, lo);
    *(bf16x8*)(dh + i) = hi;
    *(bf16x8*)(dl + i) = lo;
}

// ---- single-tensor split (o_w, late) ----
__global__ __launch_bounds__(256) void split_kernel(
    const float* __restrict__ x,
    unsigned short* __restrict__ xh, unsigned short* __restrict__ xl) {
    const long i = ((long)blockIdx.x * 256 + threadIdx.x) * 8;
    const float4 f0 = *(const float4*)(x + i);
    const float4 f1 = *(const float4*)(x + i + 4);
    bf16x8 hi, lo;
    cvt_split8(f0, f1, hi, lo);
    *(bf16x8*)(xh + i) = hi;
    *(bf16x8*)(xl + i) = lo;
}

// ---------------- MFMA GEMM: C[m,n] = sum_k A[m,k] * B^T[n,k] ----------------
// K-loop BYTE-IDENTICAL to rounds 6/8/9 (best verified: MfmaUtil ~49%, 0 bank
// conflicts). 128x128 tile, BK=32, 256 threads = 4 waves (2x2 of 64x64).
// NEW (r10): 2D supertile block swizzle — 8 consecutive blocks = 8 m-panels x
// 1 n-panel (column-major in group), A panels reused across the group's
// n-sweep => fewer L2 misses => shorter vmcnt-drain stalls. Bijective for
// gridDim.y % 8 == 0 (all our grids). No numerics change.
// SA/SB: 0 = bf16 operand (cp16 direct); 2 = pre-split hi+lo bf16 (3-term
// near-fp32 product Ah*Bh + Ah*Bl + Al*Bh).
// EPI: 0 = fp32 store; 1 = bf16 store;
//      2 = kv-split (n<2048 bf16 Cp, n>=2048 transposed bf16 Ct);
//      3 = scores->P: write bf16 exp(d-24) and atomicAdd per-row sums to rs;
//      4 = PV: write bf16 d * (1/rs[row]).
// C = (acc + bias[n]) * scale for EPI 0/1/2 (bias fp32, nullable).
template <int SA, int SB, int EPI>
__global__ __launch_bounds__(256) void mfma_gemm(
    const void* __restrict__ Ap, const void* __restrict__ A2p, int lda,
    const void* __restrict__ Bp, const void* __restrict__ B2p, int ldb,
    void* __restrict__ Cp, int ldc,
    unsigned short* __restrict__ Ct, int ldt,
    const float* __restrict__ bias, float* __restrict__ rs,
    float scale, int K) {

    __shared__ __attribute__((aligned(16))) short As[(SA ? 2 : 1) * 128 * 32];
    __shared__ __attribute__((aligned(16))) short Bs[(SB ? 2 : 1) * 128 * 32];

    const int tid = threadIdx.x;
    // ---- supertile swizzle (8 m-blocks per group, column-major in group) ----
    const int gx = gridDim.x;
    const int bid = blockIdx.y * gx + blockIdx.x;
    const int grp = bid / (8 * gx);
    const int rem = bid - grp * (8 * gx);
    const int m0 = (grp * 8 + (rem & 7)) * 128;
    const int n0 = (rem >> 3) * 128;

    const int lane = tid & 63;
    const int wave = tid >> 6;
    const int ln = lane & 15;
    const int quad = lane >> 4;
    const int wm = (wave >> 1) * 64;
    const int wn = (wave & 1) * 64;

    f32x4 acc[4][4] = {};

    // ---- loop-invariant swizzled addressing ----
    int srow_s[2], scol_s[2];
#pragma unroll
    for (int p = 0; p < 2; ++p) {
        const int P = swz(p * 4096 + tid * 16);
        srow_s[p] = P >> 6;              // tile row 0..127
        scol_s[p] = (P & 63) >> 1;       // element col 0..31
    }
    int aoffb[4], boffb[4];
#pragma unroll
    for (int t = 0; t < 4; ++t) {
        aoffb[t] = swz((wm + t * 16 + ln) * 64 + quad * 16);
        boffb[t] = swz((wn + t * 16 + ln) * 64 + quad * 16);
    }

    for (int kt = 0; kt < K; kt += 32) {
        if (kt) __syncthreads();

        // ---- stage A tile (128x32 bf16 [+lo]) ----
#pragma unroll
        for (int p = 0; p < 2; ++p) {
            const long off = (long)(m0 + srow_s[p]) * lda + kt + scol_s[p];
            char* d = (char*)As + p * 4096 + tid * 16;
            cp16((const unsigned short*)Ap + off, d);
            if (SA == 2) cp16((const unsigned short*)A2p + off, d + 8192);
        }
        // ---- stage B tile (128x32 bf16 [+lo], B^T rows) ----
#pragma unroll
        for (int p = 0; p < 2; ++p) {
            const long off = (long)(n0 + srow_s[p]) * ldb + kt + scol_s[p];
            char* d = (char*)Bs + p * 4096 + tid * 16;
            cp16((const unsigned short*)Bp + off, d);
            if (SB == 2) cp16((const unsigned short*)B2p + off, d + 8192);
        }
        __syncthreads();   // drains vmcnt (global_load_lds)

        // ---- fragments + MFMA ----
        bf16x8 ah[4], bh[4];
#pragma unroll
        for (int t = 0; t < 4; ++t)
            ah[t] = *(const bf16x8*)((const char*)As + aoffb[t]);
#pragma unroll
        for (int t = 0; t < 4; ++t)
            bh[t] = *(const bf16x8*)((const char*)Bs + boffb[t]);

#pragma unroll
        for (int i = 0; i < 4; ++i)
#pragma unroll
            for (int j = 0; j < 4; ++j)
                acc[i][j] = __builtin_amdgcn_mfma_f32_16x16x32_bf16(
                    ah[i], bh[j], acc[i][j], 0, 0, 0);

        if (SB) {
            bf16x8 bl[4];
#pragma unroll
            for (int t = 0; t < 4; ++t)
                bl[t] = *(const bf16x8*)((const char*)Bs + 8192 + boffb[t]);
#pragma unroll
            for (int i = 0; i < 4; ++i)
#pragma unroll
                for (int j = 0; j < 4; ++j)
                    acc[i][j] = __builtin_amdgcn_mfma_f32_16x16x32_bf16(
                        ah[i], bl[j], acc[i][j], 0, 0, 0);
        }
        if (SA) {
            bf16x8 al[4];
#pragma unroll
            for (int t = 0; t < 4; ++t)
                al[t] = *(const bf16x8*)((const char*)As + 8192 + aoffb[t]);
#pragma unroll
            for (int i = 0; i < 4; ++i)
#pragma unroll
                for (int j = 0; j < 4; ++j)
                    acc[i][j] = __builtin_amdgcn_mfma_f32_16x16x32_bf16(
                        al[i], bh[j], acc[i][j], 0, 0, 0);
        }
    }

    // ---- epilogue: C/D layout col=lane&15, row=quad*4+reg ----
    if (EPI == 3) {
        // fused softmax numerator: P = bf16(exp(s-24)), rs[row] += row-sum
        unsigned short* Cb = (unsigned short*)Cp;
#pragma unroll
        for (int i = 0; i < 4; ++i) {
            const int gm = m0 + wm + i * 16 + quad * 4;
            float rp[4] = {0.f, 0.f, 0.f, 0.f};
#pragma unroll
            for (int j = 0; j < 4; ++j) {
                const int gn = n0 + wn + j * 16 + ln;
                const f32x4 d = acc[i][j];
#pragma unroll
                for (int r = 0; r < 4; ++r) {
                    const float e = __expf(d[r] - 24.0f);
                    Cb[(long)(gm + r) * ldc + gn] = f2bf(e);
                    rp[r] += e;
                }
            }
            // reduce over the 16 lanes of this quad (row-uniform groups)
#pragma unroll
            for (int off = 1; off < 16; off <<= 1) {
#pragma unroll
                for (int r = 0; r < 4; ++r)
                    rp[r] += __shfl_xor(rp[r], off);
            }
            if (ln == 0) {
#pragma unroll
                for (int r = 0; r < 4; ++r)
                    atomicAdd(&rs[gm + r], rp[r]);
            }
        }
        return;
    }

#pragma unroll
    for (int i = 0; i < 4; ++i) {
        const int gm = m0 + wm + i * 16 + quad * 4;      // rows gm..gm+3
        float invr[4];
        if (EPI == 4) {
#pragma unroll
            for (int r = 0; r < 4; ++r) invr[r] = 1.0f / rs[gm + r];
        }
#pragma unroll
        for (int j = 0; j < 4; ++j) {
            const int gn = n0 + wn + j * 16 + ln;
            const float bv = bias ? bias[gn] : 0.0f;
            const f32x4 d = acc[i][j];
            if (EPI == 2 && gn >= 2048) {
                const int bt = gm >> 12;
                const int rl = gm & 4095;
                ushort4 t4;
                t4.x = f2bf((d[0] + bv) * scale);
                t4.y = f2bf((d[1] + bv) * scale);
                t4.z = f2bf((d[2] + bv) * scale);
                t4.w = f2bf((d[3] + bv) * scale);
                *(ushort4*)&Ct[((long)bt * 2048 + (gn - 2048)) * ldt + rl] = t4;
            } else if (EPI == 0) {
                float* Cf = (float*)Cp;
#pragma unroll
                for (int r = 0; r < 4; ++r)
                    Cf[(long)(gm + r) * ldc + gn] = (d[r] + bv) * scale;
            } else if (EPI == 4) {
                unsigned short* Cb = (unsigned short*)Cp;
#pragma unroll
                for (int r = 0; r < 4; ++r)
                    Cb[(long)(gm + r) * ldc + gn] = f2bf(d[r] * invr[r]);
            } else {
                unsigned short* Cb = (unsigned short*)Cp;
#pragma unroll
                for (int r = 0; r < 4; ++r)
                    Cb[(long)(gm + r) * ldc + gn] = f2bf((d[r] + bv) * scale);
            }
        }
    }
}

// ---------- RoPE trig table + rsum zeroing ----------
__global__ __launch_bounds__(256) void trig_kernel(float* __restrict__ tab,
                                                   float* __restrict__ rsum) {
    const int idx = blockIdx.x * 256 + threadIdx.x;   // < SDIM*64
    const int s = idx >> 6;
    const int i = idx & 63;
    const float f = (float)s * expf(-(float)i * 0.14391156831212787f);
    float cs, sn;
    sincosf(f, &sn, &cs);
    tab[idx] = cs;
    tab[SDIM * 64 + idx] = sn;
    if (idx < 2 * SDIM) rsum[idx] = 0.0f;
}

// ---------- fused table-driven RoPE on q and k (8 rotations per thread) ----------
__global__ __launch_bounds__(256) void rope2v_kernel(
    __hip_bfloat16* __restrict__ q, __hip_bfloat16* __restrict__ k,
    const float* __restrict__ tab, int ld) {
    long idx = (long)blockIdx.x * 256 + threadIdx.x;   // < 2*TOK*128
    const long half = (long)TOK * 128;
    __hip_bfloat16* p = (idx < half) ? q : k;          // wave-uniform select
    idx &= (half - 1);
    const int m = (int)(idx >> 7);                     // token row
    const int r = (int)(idx & 127);
    const int h = r >> 3;                              // head 0..15
    const int i0 = (r & 7) * 8;                        // i block 0,8,..,56
    const int s = m & (SDIM - 1);
    const float4 c0 = *(const float4*)&tab[s * 64 + i0];
    const float4 c1 = *(const float4*)&tab[s * 64 + i0 + 4];
    const float4 s0 = *(const float4*)&tab[SDIM * 64 + s * 64 + i0];
    const float4 s1 = *(const float4*)&tab[SDIM * 64 + s * 64 + i0 + 4];
    const float cs[8] = {c0.x, c0.y, c0.z, c0.w, c1.x, c1.y, c1.z, c1.w};
    const float sn[8] = {s0.x, s0.y, s0.z, s0.w, s1.x, s1.y, s1.z, s1.w};
    __hip_bfloat16* b = p + (long)m * ld + h * 128 + i0;
    bf16x8 v1 = *(const bf16x8*)b;          // x1[i0..i0+7]
    bf16x8 v2 = *(const bf16x8*)(b + 64);   // x2[i0..i0+7]
    bf16x8 o1, o2;
#pragma unroll
    for (int j = 0; j < 8; ++j) {
        const float x1 = bf2f(v1[j]);
        const float x2 = bf2f(v2[j]);
        o1[j] = (short)f2bf(x1 * cs[j] - x2 * sn[j]);
        o2[j] = (short)f2bf(x2 * cs[j] + x1 * sn[j]);
    }
    *(bf16x8*)b = o1;
    *(bf16x8*)(b + 64) = o2;
}

extern "C" void kernel_launch(void* const* d_in, const int* in_sizes, int n_in,
                              void* d_out, int out_size, void* d_ws, size_t ws_size,
                              hipStream_t stream) {
    const float* x    = (const float*)d_in[0];
    const float* q_w  = (const float*)d_in[1];
    const float* q_b  = (const float*)d_in[2];
    const float* kv_w = (const float*)d_in[3];
    const float* kv_b = (const float*)d_in[4];
    const float* o_w  = (const float*)d_in[5];
    float* out = (float*)d_out;

    // ws (112 MiB, proven mapped), time-multiplexed:
    //   [0..32M)   qo slot: phase A = kv_w hi/lo split; phase B+ = q / o bf16
    //   [32..64M)  kb slot: K bf16; after attention reused for o_w hi/lo
    //   [64..96M)  vT bf16 [2 x 2048 x 4096]
    //   [96..112M) q_w hi/lo split; after q-proj: RoPE trig table (2MB) +
    //              softmax row-sums rsum[2][4096] (32KB)
    // d_out (64 MiB) triple-duty:
    //   phase 1: xh|xl bf16 hi/lo split of x
    //   phase 2: P bf16 [4096 x 4096] (32MB, per batch)
    //   phase 3: final fp32 output (fully overwritten)
    unsigned short* qo  = (unsigned short*)d_ws;
    unsigned short* kb  = qo + (long)TOK * EDIM;
    unsigned short* vT  = kb + (long)TOK * EDIM;
    unsigned short* qwh = vT + (long)BDIM * EDIM * SDIM;
    unsigned short* qwl = qwh + (long)EDIM * EDIM;
    unsigned short* kvh = qo;
    unsigned short* kvl = kvh + (long)2 * EDIM * EDIM;
    unsigned short* owh = kb;
    unsigned short* owl = owh + (long)EDIM * EDIM;
    unsigned short* xh  = (unsigned short*)d_out;
    unsigned short* xl  = xh + (long)TOK * EDIM;
    float* trig = (float*)qwh;                 // 2MB, alive post-q-proj
    float* rsum = trig + (long)2 * SDIM * 64;  // 32KB, after trig table
    unsigned short* Pb = (unsigned short*)d_out;   // P bf16 4096x4096
    const unsigned short* nil = nullptr;

    // 0) one-time hi/lo splits of x, kv_w, q_w in a single launch
    split3_kernel<<<14336, 256, 0, stream>>>(
        x, xh, xl, kv_w, kvh, kvl, q_w, qwh, qwl);

    // 1) kv = x @ kv_w^T + kv_b (3 segments: Ah*Bh, Ah*Bl, Al*Bh)
    mfma_gemm<2, 2, 2><<<dim3(2 * EDIM / 128, TOK / 128), 256, 0, stream>>>(
        xh, xl, EDIM, kvh, kvl, EDIM, kb, EDIM, vT, SDIM,
        kv_b, nullptr, 1.0f, EDIM);

    // 2) q = (x @ q_w^T + q_b) * scale
    mfma_gemm<2, 2, 1><<<dim3(EDIM / 128, TOK / 128), 256, 0, stream>>>(
        xh, xl, EDIM, qwh, qwl, EDIM, qo, EDIM, nullptr, 0,
        q_b, nullptr, QK_SCALE, EDIM);

    // 3) RoPE: trig table + rsum zero (into dead q_w-split region), then rope
    trig_kernel<<<SDIM * 64 / 256, 256, 0, stream>>>(trig, rsum);
    rope2v_kernel<<<(long)2 * TOK * 128 / 256, 256, 0, stream>>>(
        (__hip_bfloat16*)qo, (__hip_bfloat16*)kb, trig, EDIM);

    // 4) per-batch attention with fused softmax (no separate softmax kernel)
    for (int b = 0; b < BDIM; ++b) {
        const long ro = (long)b * SDIM * EDIM;
        float* rs = rsum + b * SDIM;

        // P = exp(q_b @ k_b^T - 24) bf16 + row-sums  (EPI=3; 1024 blocks)
        mfma_gemm<0, 0, 3><<<dim3(SDIM / 128, SDIM / 128), 256, 0, stream>>>(
            qo + ro, nil, EDIM, kb + ro, nil, EDIM,
            Pb, SDIM, nullptr, 0, nullptr, rs, 1.0f, EDIM);

        // o_b = (P @ (VT)^T) / rowsum  (EPI=4; 512 blocks)
        mfma_gemm<0, 0, 4><<<dim3(EDIM / 128, SDIM / 128), 256, 0, stream>>>(
            Pb, nil, SDIM,
            vT + b * (long)EDIM * SDIM, nil, SDIM,
            qo + ro, EDIM, nullptr, 0, nullptr, rs, 1.0f, SDIM);
    }

    // 5) out = o @ o_w^T -> fp32 (overwrites all of d_out; kb slot dead)
    split_kernel<<<(long)EDIM * EDIM / 2048, 256, 0, stream>>>(o_w, owh, owl);
    mfma_gemm<0, 2, 0><<<dim3(EDIM / 128, TOK / 128), 256, 0, stream>>>(
        qo, nil, EDIM, owh, owl, EDIM, out, EDIM, nullptr, 0,
        nullptr, nullptr, 1.0f, EDIM);
}

// Round 11
// 1309.975 us; speedup vs baseline: 1.0267x; 1.0267x over previous
//
#include <hip/hip_runtime.h>
#include <hip/hip_bf16.h>

#define BDIM 2
#define SDIM 4096
#define EDIM 2048
#define TOK (BDIM * SDIM)       // 8192
#define QK_SCALE 0.08838834764831845f  // 128^-0.5

typedef short bf16x8 __attribute__((ext_vector_type(8)));
typedef float f32x4 __attribute__((ext_vector_type(4)));

__device__ __forceinline__ unsigned short f2bf(float f) {
    unsigned u = __float_as_uint(f);
    u += 0x7FFF + ((u >> 16) & 1);          // RNE; inputs finite
    return (unsigned short)(u >> 16);
}

__device__ __forceinline__ float bf2f(short s) {
    return __uint_as_float(((unsigned)(unsigned short)s) << 16);
}

// fp32x8 -> bf16 hi + bf16 lo (residual), for near-fp32 MFMA via 3-term split
__device__ __forceinline__ void cvt_split8(const float4 a, const float4 b,
                                           bf16x8& hi, bf16x8& lo) {
    float f[8] = {a.x, a.y, a.z, a.w, b.x, b.y, b.z, b.w};
#pragma unroll
    for (int i = 0; i < 8; ++i) {
        const unsigned short h = f2bf(f[i]);
        hi[i] = (short)h;
        const float hf = __uint_as_float(((unsigned)h) << 16);
        lo[i] = (short)f2bf(f[i] - hf);
    }
}

// async 16B global -> LDS (wave-uniform base + lane*16 dest; per-lane source ok)
__device__ __forceinline__ void cp16(const void* g, void* l) {
    __builtin_amdgcn_global_load_lds(
        (const __attribute__((address_space(1))) unsigned int*)g,
        (__attribute__((address_space(3))) unsigned int*)l, 16, 0, 0);
}

// LDS anti-bank-conflict involution on 64B rows (XOR row bits[3:1] -> byte
// bits[6:4]); 16B-granularity-preserving, self-inverse. Proven bit-correct
// with SQ_LDS_BANK_CONFLICT -> 0 in rounds 4/5/6/8/9.
__device__ __forceinline__ int swz(int L) { return L ^ (((L >> 7) & 7) << 4); }

// ---- one-time fp32 -> bf16 hi/lo splits, 3 tensors in one launch ----
__global__ __launch_bounds__(256) void split3_kernel(
    const float* __restrict__ x,  unsigned short* __restrict__ xh,  unsigned short* __restrict__ xl,
    const float* __restrict__ w1, unsigned short* __restrict__ w1h, unsigned short* __restrict__ w1l,
    const float* __restrict__ w2, unsigned short* __restrict__ w2h, unsigned short* __restrict__ w2l) {
    long i = ((long)blockIdx.x * 256 + threadIdx.x) * 8;
    const long n0 = (long)TOK * EDIM;          // 16M elems
    const long n1 = (long)2 * EDIM * EDIM;     // 8M elems
    const float* src; unsigned short *dh, *dl;
    if (i < n0)           { src = x;  dh = xh;  dl = xl;  }
    else if (i < n0 + n1) { i -= n0;      src = w1; dh = w1h; dl = w1l; }
    else                  { i -= n0 + n1; src = w2; dh = w2h; dl = w2l; }
    const float4 f0 = *(const float4*)(src + i);
    const float4 f1 = *(const float4*)(src + i + 4);
    bf16x8 hi, lo;
    cvt_split8(f0, f1, hi, lo);
    *(bf16x8*)(dh + i) = hi;
    *(bf16x8*)(dl + i) = lo;
}

// ---- single-tensor split (o_w, late) ----
__global__ __launch_bounds__(256) void split_kernel(
    const float* __restrict__ x,
    unsigned short* __restrict__ xh, unsigned short* __restrict__ xl) {
    const long i = ((long)blockIdx.x * 256 + threadIdx.x) * 8;
    const float4 f0 = *(const float4*)(x + i);
    const float4 f1 = *(const float4*)(x + i + 4);
    bf16x8 hi, lo;
    cvt_split8(f0, f1, hi, lo);
    *(bf16x8*)(xh + i) = hi;
    *(bf16x8*)(xl + i) = lo;
}

// ---------------- MFMA GEMM: C[m,n] = sum_k A[m,k] * B^T[n,k] ----------------
// K-loop BYTE-IDENTICAL to rounds 6/8/9 (best verified: MfmaUtil ~49%, 0 bank
// conflicts; r10's supertile swizzle REVERTED — it raised FETCH 630MB->1GB).
// 128x128 tile, BK=32, 256 threads = 4 waves (2x2 of 64x64).
// bstrB: per-batch element stride on the B operand — the block's batch is
// m0>>12 (block-uniform); 0 for plain GEMMs. Enables batch-merged attention
// dispatches (scores/PV over all 8192 rows in one launch).
// SA/SB: 0 = bf16 operand (cp16 direct); 2 = pre-split hi+lo bf16 (3-term
// near-fp32 product Ah*Bh + Ah*Bl + Al*Bh).
// EPI: 0 = fp32 store; 1 = bf16 store;
//      2 = kv-split (n<2048 bf16 Cp, n>=2048 transposed bf16 Ct);
//      3 = scores->P: write bf16 exp(d-24) and atomicAdd per-row sums to
//          rs[gm] (global row index; rs laid out [batch][4096] contiguous);
//      4 = PV: write bf16 d * (1/rs[gm]).
// C = (acc + bias[n]) * scale for EPI 0/1/2 (bias fp32, nullable).
template <int SA, int SB, int EPI>
__global__ __launch_bounds__(256) void mfma_gemm(
    const void* __restrict__ Ap, const void* __restrict__ A2p, int lda,
    const void* __restrict__ Bp, const void* __restrict__ B2p, int ldb,
    long bstrB,
    void* __restrict__ Cp, int ldc,
    unsigned short* __restrict__ Ct, int ldt,
    const float* __restrict__ bias, float* __restrict__ rs,
    float scale, int K) {

    __shared__ __attribute__((aligned(16))) short As[(SA ? 2 : 1) * 128 * 32];
    __shared__ __attribute__((aligned(16))) short Bs[(SB ? 2 : 1) * 128 * 32];

    const int tid = threadIdx.x;
    const int m0 = blockIdx.y * 128;
    const int n0 = blockIdx.x * 128;
    const long bofs = (long)(m0 >> 12) * bstrB;   // batch offset on B

    const int lane = tid & 63;
    const int wave = tid >> 6;
    const int ln = lane & 15;
    const int quad = lane >> 4;
    const int wm = (wave >> 1) * 64;
    const int wn = (wave & 1) * 64;

    f32x4 acc[4][4] = {};

    // ---- loop-invariant swizzled addressing ----
    int srow_s[2], scol_s[2];
#pragma unroll
    for (int p = 0; p < 2; ++p) {
        const int P = swz(p * 4096 + tid * 16);
        srow_s[p] = P >> 6;              // tile row 0..127
        scol_s[p] = (P & 63) >> 1;       // element col 0..31
    }
    int aoffb[4], boffb[4];
#pragma unroll
    for (int t = 0; t < 4; ++t) {
        aoffb[t] = swz((wm + t * 16 + ln) * 64 + quad * 16);
        boffb[t] = swz((wn + t * 16 + ln) * 64 + quad * 16);
    }

    for (int kt = 0; kt < K; kt += 32) {
        if (kt) __syncthreads();

        // ---- stage A tile (128x32 bf16 [+lo]) ----
#pragma unroll
        for (int p = 0; p < 2; ++p) {
            const long off = (long)(m0 + srow_s[p]) * lda + kt + scol_s[p];
            char* d = (char*)As + p * 4096 + tid * 16;
            cp16((const unsigned short*)Ap + off, d);
            if (SA == 2) cp16((const unsigned short*)A2p + off, d + 8192);
        }
        // ---- stage B tile (128x32 bf16 [+lo], B^T rows) ----
#pragma unroll
        for (int p = 0; p < 2; ++p) {
            const long off = bofs + (long)(n0 + srow_s[p]) * ldb + kt + scol_s[p];
            char* d = (char*)Bs + p * 4096 + tid * 16;
            cp16((const unsigned short*)Bp + off, d);
            if (SB == 2) cp16((const unsigned short*)B2p + off, d + 8192);
        }
        __syncthreads();   // drains vmcnt (global_load_lds)

        // ---- fragments + MFMA ----
        bf16x8 ah[4], bh[4];
#pragma unroll
        for (int t = 0; t < 4; ++t)
            ah[t] = *(const bf16x8*)((const char*)As + aoffb[t]);
#pragma unroll
        for (int t = 0; t < 4; ++t)
            bh[t] = *(const bf16x8*)((const char*)Bs + boffb[t]);

#pragma unroll
        for (int i = 0; i < 4; ++i)
#pragma unroll
            for (int j = 0; j < 4; ++j)
                acc[i][j] = __builtin_amdgcn_mfma_f32_16x16x32_bf16(
                    ah[i], bh[j], acc[i][j], 0, 0, 0);

        if (SB) {
            bf16x8 bl[4];
#pragma unroll
            for (int t = 0; t < 4; ++t)
                bl[t] = *(const bf16x8*)((const char*)Bs + 8192 + boffb[t]);
#pragma unroll
            for (int i = 0; i < 4; ++i)
#pragma unroll
                for (int j = 0; j < 4; ++j)
                    acc[i][j] = __builtin_amdgcn_mfma_f32_16x16x32_bf16(
                        ah[i], bl[j], acc[i][j], 0, 0, 0);
        }
        if (SA) {
            bf16x8 al[4];
#pragma unroll
            for (int t = 0; t < 4; ++t)
                al[t] = *(const bf16x8*)((const char*)As + 8192 + aoffb[t]);
#pragma unroll
            for (int i = 0; i < 4; ++i)
#pragma unroll
                for (int j = 0; j < 4; ++j)
                    acc[i][j] = __builtin_amdgcn_mfma_f32_16x16x32_bf16(
                        al[i], bh[j], acc[i][j], 0, 0, 0);
        }
    }

    // ---- epilogue: C/D layout col=lane&15, row=quad*4+reg ----
    if (EPI == 3) {
        // fused softmax numerator: P = bf16(exp(s-24)), rs[row] += row-sum
        unsigned short* Cb = (unsigned short*)Cp;
#pragma unroll
        for (int i = 0; i < 4; ++i) {
            const int gm = m0 + wm + i * 16 + quad * 4;
            float rp[4] = {0.f, 0.f, 0.f, 0.f};
#pragma unroll
            for (int j = 0; j < 4; ++j) {
                const int gn = n0 + wn + j * 16 + ln;
                const f32x4 d = acc[i][j];
#pragma unroll
                for (int r = 0; r < 4; ++r) {
                    const float e = __expf(d[r] - 24.0f);
                    Cb[(long)(gm + r) * ldc + gn] = f2bf(e);
                    rp[r] += e;
                }
            }
            // reduce over the 16 lanes of this quad (row-uniform groups)
#pragma unroll
            for (int off = 1; off < 16; off <<= 1) {
#pragma unroll
                for (int r = 0; r < 4; ++r)
                    rp[r] += __shfl_xor(rp[r], off);
            }
            if (ln == 0) {
#pragma unroll
                for (int r = 0; r < 4; ++r)
                    atomicAdd(&rs[gm + r], rp[r]);
            }
        }
        return;
    }

#pragma unroll
    for (int i = 0; i < 4; ++i) {
        const int gm = m0 + wm + i * 16 + quad * 4;      // rows gm..gm+3
        float invr[4];
        if (EPI == 4) {
#pragma unroll
            for (int r = 0; r < 4; ++r) invr[r] = 1.0f / rs[gm + r];
        }
#pragma unroll
        for (int j = 0; j < 4; ++j) {
            const int gn = n0 + wn + j * 16 + ln;
            const float bv = bias ? bias[gn] : 0.0f;
            const f32x4 d = acc[i][j];
            if (EPI == 2 && gn >= 2048) {
                const int bt = gm >> 12;
                const int rl = gm & 4095;
                ushort4 t4;
                t4.x = f2bf((d[0] + bv) * scale);
                t4.y = f2bf((d[1] + bv) * scale);
                t4.z = f2bf((d[2] + bv) * scale);
                t4.w = f2bf((d[3] + bv) * scale);
                *(ushort4*)&Ct[((long)bt * 2048 + (gn - 2048)) * ldt + rl] = t4;
            } else if (EPI == 0) {
                float* Cf = (float*)Cp;
#pragma unroll
                for (int r = 0; r < 4; ++r)
                    Cf[(long)(gm + r) * ldc + gn] = (d[r] + bv) * scale;
            } else if (EPI == 4) {
                unsigned short* Cb = (unsigned short*)Cp;
#pragma unroll
                for (int r = 0; r < 4; ++r)
                    Cb[(long)(gm + r) * ldc + gn] = f2bf(d[r] * invr[r]);
            } else {
                unsigned short* Cb = (unsigned short*)Cp;
#pragma unroll
                for (int r = 0; r < 4; ++r)
                    Cb[(long)(gm + r) * ldc + gn] = f2bf((d[r] + bv) * scale);
            }
        }
    }
}

// ---------- RoPE trig table + rsum zeroing ----------
__global__ __launch_bounds__(256) void trig_kernel(float* __restrict__ tab,
                                                   float* __restrict__ rsum) {
    const int idx = blockIdx.x * 256 + threadIdx.x;   // < SDIM*64
    const int s = idx >> 6;
    const int i = idx & 63;
    const float f = (float)s * expf(-(float)i * 0.14391156831212787f);
    float cs, sn;
    sincosf(f, &sn, &cs);
    tab[idx] = cs;
    tab[SDIM * 64 + idx] = sn;
    if (idx < 2 * SDIM) rsum[idx] = 0.0f;
}

// ---------- fused table-driven RoPE on q and k (8 rotations per thread) ----------
__global__ __launch_bounds__(256) void rope2v_kernel(
    __hip_bfloat16* __restrict__ q, __hip_bfloat16* __restrict__ k,
    const float* __restrict__ tab, int ld) {
    long idx = (long)blockIdx.x * 256 + threadIdx.x;   // < 2*TOK*128
    const long half = (long)TOK * 128;
    __hip_bfloat16* p = (idx < half) ? q : k;          // wave-uniform select
    idx &= (half - 1);
    const int m = (int)(idx >> 7);                     // token row
    const int r = (int)(idx & 127);
    const int h = r >> 3;                              // head 0..15
    const int i0 = (r & 7) * 8;                        // i block 0,8,..,56
    const int s = m & (SDIM - 1);
    const float4 c0 = *(const float4*)&tab[s * 64 + i0];
    const float4 c1 = *(const float4*)&tab[s * 64 + i0 + 4];
    const float4 s0 = *(const float4*)&tab[SDIM * 64 + s * 64 + i0];
    const float4 s1 = *(const float4*)&tab[SDIM * 64 + s * 64 + i0 + 4];
    const float cs[8] = {c0.x, c0.y, c0.z, c0.w, c1.x, c1.y, c1.z, c1.w};
    const float sn[8] = {s0.x, s0.y, s0.z, s0.w, s1.x, s1.y, s1.z, s1.w};
    __hip_bfloat16* b = p + (long)m * ld + h * 128 + i0;
    bf16x8 v1 = *(const bf16x8*)b;          // x1[i0..i0+7]
    bf16x8 v2 = *(const bf16x8*)(b + 64);   // x2[i0..i0+7]
    bf16x8 o1, o2;
#pragma unroll
    for (int j = 0; j < 8; ++j) {
        const float x1 = bf2f(v1[j]);
        const float x2 = bf2f(v2[j]);
        o1[j] = (short)f2bf(x1 * cs[j] - x2 * sn[j]);
        o2[j] = (short)f2bf(x2 * cs[j] + x1 * sn[j]);
    }
    *(bf16x8*)b = o1;
    *(bf16x8*)(b + 64) = o2;
}

extern "C" void kernel_launch(void* const* d_in, const int* in_sizes, int n_in,
                              void* d_out, int out_size, void* d_ws, size_t ws_size,
                              hipStream_t stream) {
    const float* x    = (const float*)d_in[0];
    const float* q_w  = (const float*)d_in[1];
    const float* q_b  = (const float*)d_in[2];
    const float* kv_w = (const float*)d_in[3];
    const float* kv_b = (const float*)d_in[4];
    const float* o_w  = (const float*)d_in[5];
    float* out = (float*)d_out;

    // ws (112 MiB, proven mapped), time-multiplexed:
    //   [0..32M)   qo slot: phase A = kv_w hi/lo split; phase B+ = q / o bf16
    //   [32..64M)  kb slot: K bf16; after attention reused for o_w hi/lo
    //   [64..96M)  vT bf16 [2 x 2048 x 4096]
    //   [96..112M) q_w hi/lo split; after q-proj: RoPE trig table (2MB) +
    //              softmax row-sums rsum[2][4096] (32KB)
    // d_out (64 MiB) triple-duty:
    //   phase 1: xh|xl bf16 hi/lo split of x
    //   phase 2: P bf16 [8192 x 4096] (64MB, BOTH batches — merged dispatch)
    //   phase 3: final fp32 output (fully overwritten)
    unsigned short* qo  = (unsigned short*)d_ws;
    unsigned short* kb  = qo + (long)TOK * EDIM;
    unsigned short* vT  = kb + (long)TOK * EDIM;
    unsigned short* qwh = vT + (long)BDIM * EDIM * SDIM;
    unsigned short* qwl = qwh + (long)EDIM * EDIM;
    unsigned short* kvh = qo;
    unsigned short* kvl = kvh + (long)2 * EDIM * EDIM;
    unsigned short* owh = kb;
    unsigned short* owl = owh + (long)EDIM * EDIM;
    unsigned short* xh  = (unsigned short*)d_out;
    unsigned short* xl  = xh + (long)TOK * EDIM;
    float* trig = (float*)qwh;                 // 2MB, alive post-q-proj
    float* rsum = trig + (long)2 * SDIM * 64;  // 32KB, [batch][4096] contiguous
    unsigned short* Pb = (unsigned short*)d_out;   // P bf16 [8192][4096]
    const unsigned short* nil = nullptr;

    // 0) one-time hi/lo splits of x, kv_w, q_w in a single launch
    split3_kernel<<<14336, 256, 0, stream>>>(
        x, xh, xl, kv_w, kvh, kvl, q_w, qwh, qwl);

    // 1) kv = x @ kv_w^T + kv_b (3 segments: Ah*Bh, Ah*Bl, Al*Bh)
    mfma_gemm<2, 2, 2><<<dim3(2 * EDIM / 128, TOK / 128), 256, 0, stream>>>(
        xh, xl, EDIM, kvh, kvl, EDIM, 0, kb, EDIM, vT, SDIM,
        kv_b, nullptr, 1.0f, EDIM);

    // 2) q = (x @ q_w^T + q_b) * scale
    mfma_gemm<2, 2, 1><<<dim3(EDIM / 128, TOK / 128), 256, 0, stream>>>(
        xh, xl, EDIM, qwh, qwl, EDIM, 0, qo, EDIM, nullptr, 0,
        q_b, nullptr, QK_SCALE, EDIM);

    // 3) RoPE: trig table + rsum zero (into dead q_w-split region), then rope
    trig_kernel<<<SDIM * 64 / 256, 256, 0, stream>>>(trig, rsum);
    rope2v_kernel<<<(long)2 * TOK * 128 / 256, 256, 0, stream>>>(
        (__hip_bfloat16*)qo, (__hip_bfloat16*)kb, trig, EDIM);

    // 4) attention, batch-merged dispatches (batch = row>>12 via bstrB)
    // P = exp(q @ k_b^T - 24) bf16 [8192][4096] + row-sums  (2048 blocks)
    mfma_gemm<0, 0, 3><<<dim3(SDIM / 128, TOK / 128), 256, 0, stream>>>(
        qo, nil, EDIM, kb, nil, EDIM, (long)SDIM * EDIM,
        Pb, SDIM, nullptr, 0, nullptr, rsum, 1.0f, EDIM);

    // o = (P @ (VT_b)^T) / rowsum -> qo rows  (1024 blocks)
    mfma_gemm<0, 0, 4><<<dim3(EDIM / 128, TOK / 128), 256, 0, stream>>>(
        Pb, nil, SDIM, vT, nil, SDIM, (long)EDIM * SDIM,
        qo, EDIM, nullptr, 0, nullptr, rsum, 1.0f, SDIM);

    // 5) out = o @ o_w^T -> fp32 (overwrites all of d_out; kb slot dead)
    split_kernel<<<(long)EDIM * EDIM / 2048, 256, 0, stream>>>(o_w, owh, owl);
    mfma_gemm<0, 2, 0><<<dim3(EDIM / 128, TOK / 128), 256, 0, stream>>>(
        qo, nil, EDIM, owh, owl, EDIM, 0, out, EDIM, nullptr, 0,
        nullptr, nullptr, 1.0f, EDIM);
}